// Round 4
// baseline (949.296 us; speedup 1.0000x reference)
//
#include <hip/hip_runtime.h>

// Problem constants (match reference setup_inputs)
constexpr int L = 64;
constexpr int P = 32768;
constexpr int N = L * P;          // 2,097,152 nodes
constexpr int E_PER = 262144;     // edges per non-source level
constexpr int NLEVELS = L - 1;    // 63 edge levels

constexpr int BLOCK = 1024;                 // 16 waves/block
constexpr int GRID  = E_PER / BLOCK;        // 256 blocks -> 1/CU, 16 waves/CU
constexpr int GROUPS = 16;                  // arrival fan-in lines
constexpr int GROUP_SIZE = GRID / GROUPS;   // 16 blocks per group
constexpr int SLOT = 32;                    // uints per slot = 128 B (own line)

// Workspace layout (uint slots, 128 B apart):
//   slot 0       : global arrival counter (leaders only, 16 adds/level)
//   slot 1       : single release flag (polled by all 256 reps)
//   slots 2..17  : per-group arrival counters (16 adds each, parallel lines)
// Counters are MONOTONE across the 63 barriers (no reset -> no ABA);
// ws_init re-zeroes before each replay.
__global__ void __launch_bounds__(256)
ws_init(unsigned* __restrict__ ws) {
    for (int k = threadIdx.x; k < (2 + GROUPS) * SLOT; k += 256) ws[k] = 0u;
}

// Persistent kernel, fence-free barriers (validated bit-exact in R2/R3).
// Coherence scheme:
//  - atomicMax (agent scope) executes at the cross-XCD coherence point.
//  - gathers of `out` are relaxed AGENT-scope atomic loads (sc1): bypass the
//    non-coherent per-XCD L2, read the coherence point (out is 8 MB, L3-hot).
//  - plain init stores published ONCE via __threadfence at barrier 0.
//  - per-wave s_waitcnt vmcnt(0) at __syncthreads() orders "my level-l
//    atomics complete" before the block's barrier arrival.
// R4 change vs R3: barrier population 1024 -> 256 blocks (same lane count),
// flat single-word release instead of 32-flag fan-out, GROUPS 32 -> 16.
__global__ void __launch_bounds__(BLOCK, 1)
pathfinder_fused(const float4* __restrict__ hdr4,
                 const int* __restrict__ src,
                 const int* __restrict__ dst,
                 float* __restrict__ out,
                 unsigned* __restrict__ ws) {
    const int b = blockIdx.x;
    const int t = b * BLOCK + threadIdx.x;   // 0 .. E_PER-1
    const int g = b >> 4;                    // group = 16 consecutive blocks

    unsigned* const gcnt   = ws;                   // global counter (leaders)
    unsigned* const grel   = ws + SLOT;            // single release word
    unsigned* const grpcnt = ws + (2 + g) * SLOT;  // my group's arrival line

    // Phase 0: out = hdr. N/4 = 524288 float4s, 2 per thread, coalesced.
    {
        float4* __restrict__ out4 = reinterpret_cast<float4*>(out);
        out4[t]         = hdr4[t];
        out4[t + E_PER] = hdr4[t + E_PER];
    }

    // Preload level-0 edge endpoints (coalesced, read-only).
    int si = src[t];
    int di = dst[t];

    unsigned* const outu = reinterpret_cast<unsigned*>(out);

    for (int l = 0; l < NLEVELS; ++l) {
        // ---- grid barrier #l ----
        __syncthreads();   // all 16 waves drain their stores/atomics
        if (threadIdx.x == 0) {
            if (l == 0) __threadfence();   // once: publish init stores
            // arrival: 16 parallel group lines, 16 serialized adds each
            const unsigned old = __hip_atomic_fetch_add(
                grpcnt, 1u, __ATOMIC_RELAXED, __HIP_MEMORY_SCOPE_AGENT);
            if (old == (unsigned)((l + 1) * GROUP_SIZE - 1)) {
                // group leader: 16 serialized adds on the global line
                const unsigned o2 = __hip_atomic_fetch_add(
                    gcnt, 1u, __ATOMIC_RELAXED, __HIP_MEMORY_SCOPE_AGENT);
                if (o2 == (unsigned)((l + 1) * GROUPS - 1)) {
                    // last leader: single-word release, no fan-out hop
                    __hip_atomic_store(grel, (unsigned)(l + 1),
                                       __ATOMIC_RELAXED,
                                       __HIP_MEMORY_SCOPE_AGENT);
                }
            }
            // flat spin: 256 reps poll one coherence-point line
            while (__hip_atomic_load(grel, __ATOMIC_RELAXED,
                                     __HIP_MEMORY_SCOPE_AGENT)
                   < (unsigned)(l + 1)) {
                __builtin_amdgcn_s_sleep(2);
            }
        }
        __syncthreads();

        // Level l work: coherent gather, scatter-max into level-l dst slice.
        const unsigned raw = __hip_atomic_load(
            outu + si, __ATOMIC_RELAXED, __HIP_MEMORY_SCOPE_AGENT);
        const float v = __uint_as_float(raw) + 1.0f;
        atomicMax(outu + di, __float_as_uint(v));

        // Preload next level's edges (read-only; safe across the barrier).
        if (l + 1 < NLEVELS) {
            const size_t base = (size_t)(l + 1) * E_PER;
            si = src[base + t];
            di = dst[base + t];
        }
    }
    // Kernel-end implicit system-scope release publishes the final atomics.
}

extern "C" void kernel_launch(void* const* d_in, const int* in_sizes, int n_in,
                              void* d_out, int out_size, void* d_ws, size_t ws_size,
                              hipStream_t stream) {
    const float4* hdr4 = (const float4*)d_in[0];
    const int*    src  = (const int*)d_in[1];
    const int*    dst  = (const int*)d_in[2];
    float*        out  = (float*)d_out;
    unsigned*     ws   = (unsigned*)d_ws;

    // Zero barrier counters (stream-ordered before the main kernel).
    ws_init<<<dim3(1), dim3(256), 0, stream>>>(ws);

    void* args[] = { (void*)&hdr4, (void*)&src, (void*)&dst,
                     (void*)&out, (void*)&ws };
    hipLaunchCooperativeKernel((const void*)pathfinder_fused,
                               dim3(GRID), dim3(BLOCK), args, 0, stream);
}

// Round 7
// 880.915 us; speedup vs baseline: 1.0776x; 1.0776x over previous
//
#include <hip/hip_runtime.h>

// Problem constants (match reference setup_inputs)
constexpr int L = 64;
constexpr int P = 32768;
constexpr int N = L * P;          // 2,097,152 nodes
constexpr int E_PER = 262144;     // edges per non-source level
constexpr int NLEVELS = L - 1;    // 63 edge levels

constexpr int BLOCK = 1024;                 // 16 waves/block, 1 block/CU
constexpr int GRID  = E_PER / BLOCK;        // 256 blocks
constexpr int GROUPS = 16;                  // arrival fan-in lines
constexpr int GROUP_SIZE = GRID / GROUPS;   // 16 blocks per group
constexpr int SLOT = 32;                    // uints per slot = 128 B (own line)

// Native vector type (HIP_vector_type is rejected by nontemporal builtins).
typedef float vfloat4 __attribute__((ext_vector_type(4)));

// Workspace layout (uint slots, 128 B apart):
//   slot 0       : global arrival counter (leaders)
//   slot 1       : single release word (polled by 256 reps)
//   slots 2..17  : per-group arrival counters
// Counters are MONOTONE across barriers (no reset -> no ABA).
__global__ void __launch_bounds__(256)
ws_init(unsigned* __restrict__ ws) {
    for (int k = threadIdx.x; k < (2 + GROUPS) * SLOT; k += 256) ws[k] = 0u;
}

// Split-phase grid barrier, tid0-only, between __syncthreads pairs.
// bar is 1-based: B_k <-> bar = k+1.
__device__ __forceinline__ void bar_arrive(unsigned bar, unsigned* gcnt,
                                           unsigned* grel, unsigned* grpcnt) {
    const unsigned old = __hip_atomic_fetch_add(
        grpcnt, 1u, __ATOMIC_RELAXED, __HIP_MEMORY_SCOPE_AGENT);
    if (old == bar * GROUP_SIZE - 1) {                 // group leader
        const unsigned o2 = __hip_atomic_fetch_add(
            gcnt, 1u, __ATOMIC_RELAXED, __HIP_MEMORY_SCOPE_AGENT);
        if (o2 == bar * GROUPS - 1)                    // last leader: release
            __hip_atomic_store(grel, bar, __ATOMIC_RELAXED,
                               __HIP_MEMORY_SCOPE_AGENT);
    }
}
__device__ __forceinline__ void bar_wait(unsigned bar, unsigned* grel) {
    while (__hip_atomic_load(grel, __ATOMIC_RELAXED,
                             __HIP_MEMORY_SCOPE_AGENT) < bar)
        __builtin_amdgcn_s_sleep(1);
}

// Memory plan (evidence-driven):
//  - atomicMax: agent scope (sc1) -> executes at the cross-XCD coherence
//    point, WRITE-THROUGH / NO-ALLOCATE (R3 counters: WRITE_SIZE = 63 x
//    262144 x 32B, i.e. one HBM sector per atomic, no L2 coalescing).
//  - gathers: PLAIN CACHED loads. Safe: a line of level m is first
//    plain-touched only after barrier B_m (src-range guarantees), and after
//    B_m the level is immutable -> cached copies are never stale. Init goes
//    through sc1 stores so L2 never holds init lines; dispatch acquire
//    invalidated leftover lines from fill/previous launches (proven by R0's
//    multi-launch passing with plain gathers).
//  - split-phase overlap: set l+1 edges with src < (l+1)*P (~93% avg)
//    execute between arrive(B_{l+1}) and wait(B_{l+1}), hiding under the
//    previous level's atomic drain + release propagation. Only the fresh
//    fraction (src in level l+1, 1/(l+2)) remains on the critical path.
__global__ void __launch_bounds__(BLOCK, 1)
pathfinder_fused(const float* __restrict__ hdr,
                 const int* __restrict__ src,
                 const int* __restrict__ dst,
                 float* __restrict__ out,
                 unsigned* __restrict__ ws) {
    const int b   = blockIdx.x;
    const int tid = threadIdx.x;
    const int t   = b * BLOCK + tid;          // 0 .. E_PER-1
    const int g   = b >> 4;                   // 16 blocks per group

    unsigned* const gcnt   = ws;
    unsigned* const grel   = ws + SLOT;
    unsigned* const grpcnt = ws + (2 + g) * SLOT;
    unsigned* const outu   = reinterpret_cast<unsigned*>(out);

    // ---- init: out = hdr via sc1 stores (coherence point, no dirty L2) ----
    {
        const vfloat4* hdr4 = reinterpret_cast<const vfloat4*>(hdr);
        const vfloat4 a = __builtin_nontemporal_load(hdr4 + t);
        const vfloat4 c = __builtin_nontemporal_load(hdr4 + t + E_PER);
        #pragma unroll
        for (int j = 0; j < 4; ++j) {
            __hip_atomic_store(outu + 4 * t + j, __float_as_uint(a[j]),
                               __ATOMIC_RELAXED, __HIP_MEMORY_SCOPE_AGENT);
            __hip_atomic_store(outu + 4 * (t + E_PER) + j, __float_as_uint(c[j]),
                               __ATOMIC_RELAXED, __HIP_MEMORY_SCOPE_AGENT);
        }
    }

    // Preload sets 0 and 1 (read-only; nt hint preserves L2 for out lines).
    int si0 = __builtin_nontemporal_load(src + t);
    int di0 = __builtin_nontemporal_load(dst + t);
    int si1 = __builtin_nontemporal_load(src + E_PER + t);
    int di1 = __builtin_nontemporal_load(dst + E_PER + t);

    // ---- B_0: init published (syncthreads drains the sc1 stores) ----
    __syncthreads();
    if (tid == 0) { bar_arrive(1u, gcnt, grel, grpcnt); bar_wait(1u, grel); }
    __syncthreads();

    for (int l = 0; l < NLEVELS; ++l) {
        // ---- phase A: fresh part of set l (l==0: all lanes) ----
        // si0 >= l*P means src in level l, finalized at B_l (just observed).
        if (si0 >= l * P) {
            const float v = out[si0] + 1.0f;          // plain cached gather
            atomicMax(outu + di0, __float_as_uint(v));
        }
        if (l == NLEVELS - 1) break;   // last set: kernel end publishes

        __syncthreads();               // drain ALL set-l atomics (vmcnt 0)
        if (tid == 0) bar_arrive((unsigned)(l + 2), gcnt, grel, grpcnt);

        // ---- overlap window: set l+1 non-fresh + preload set l+2 ----
        int si2 = 0, di2 = 0;
        if (l + 2 < NLEVELS) {
            const size_t base = (size_t)(l + 2) * E_PER;
            si2 = __builtin_nontemporal_load(src + base + t);
            di2 = __builtin_nontemporal_load(dst + base + t);
        }
        // src in levels <= l: final since B_l -> safe NOW, off critical path.
        // (their writes drain at next iteration's phase-A __syncthreads,
        //  before this block's arrival at B_{l+2}; readers gated by B_{l+2}.)
        if (si1 < (l + 1) * P) {
            const float v = out[si1] + 1.0f;          // plain cached gather
            atomicMax(outu + di1, __float_as_uint(v));
        }

        if (tid == 0) bar_wait((unsigned)(l + 2), grel);
        __syncthreads();               // B_{l+1} observed block-wide

        si0 = si1; di0 = di1; si1 = si2; di1 = di2;
    }
}

extern "C" void kernel_launch(void* const* d_in, const int* in_sizes, int n_in,
                              void* d_out, int out_size, void* d_ws, size_t ws_size,
                              hipStream_t stream) {
    const float* hdr = (const float*)d_in[0];
    const int*   src = (const int*)d_in[1];
    const int*   dst = (const int*)d_in[2];
    float*       out = (float*)d_out;
    unsigned*    ws  = (unsigned*)d_ws;

    // Zero barrier counters (stream-ordered before the main kernel).
    ws_init<<<dim3(1), dim3(256), 0, stream>>>(ws);

    void* args[] = { (void*)&hdr, (void*)&src, (void*)&dst,
                     (void*)&out, (void*)&ws };
    (void)hipLaunchCooperativeKernel((const void*)pathfinder_fused,
                                     dim3(GRID), dim3(BLOCK), args, 0, stream);
}